// Round 2
// 2427.776 us; speedup vs baseline: 1.3591x; 1.3591x over previous
//
#include <hip/hip_runtime.h>
#include <math.h>

// Problem constants
#define B 64
#define S 64
#define T 15
#define H 1024
#define V 50257
// SOS token = 0

typedef __attribute__((ext_vector_type(8))) short short8;
typedef __attribute__((ext_vector_type(4))) float f32x4;

// fp32 -> bf16 with round-to-nearest-even
__device__ __forceinline__ short f2bf(float x) {
  unsigned u = __float_as_uint(x);
  u += 0x7fffu + ((u >> 16) & 1u);
  return (short)(u >> 16);
}

__device__ __forceinline__ float fast_sigmoid(float x) {
  return 1.f / (1.f + __expf(-x));
}
__device__ __forceinline__ float fast_tanh(float x) {
  x = fminf(15.f, fmaxf(-15.f, x));
  float e = __expf(2.f * x);
  return (e - 1.f) / (e + 1.f);
}

// Pack 16 fp32 (4 float4s) -> 16 bf16 (2 short8) at dst, dst+8
__device__ __forceinline__ void pack16(const float4* __restrict__ p, short* dst) {
  float4 v0 = p[0], v1 = p[1], v2 = p[2], v3 = p[3];
  union PK { short8 v; short s[8]; } lo, hi;
  lo.s[0] = f2bf(v0.x); lo.s[1] = f2bf(v0.y); lo.s[2] = f2bf(v0.z); lo.s[3] = f2bf(v0.w);
  lo.s[4] = f2bf(v1.x); lo.s[5] = f2bf(v1.y); lo.s[6] = f2bf(v1.z); lo.s[7] = f2bf(v1.w);
  hi.s[0] = f2bf(v2.x); hi.s[1] = f2bf(v2.y); hi.s[2] = f2bf(v2.z); hi.s[3] = f2bf(v2.w);
  hi.s[4] = f2bf(v3.x); hi.s[5] = f2bf(v3.y); hi.s[6] = f2bf(v3.z); hi.s[7] = f2bf(v3.w);
  *(short8*)dst = lo.v;
  *(short8*)(dst + 8) = hi.v;
}

// ---------------------------------------------------------------------------
// Original (verified) generic MFMA GEMM, fp32 A and B, split-B. Used only for
// the two one-time setup GEMMs (Uk, gi_e).
// ---------------------------------------------------------------------------
__global__ __launch_bounds__(256) void gemm_mfma(
    const float* __restrict__ A, int lda,
    const float* __restrict__ Bt, int ldb,
    const float* __restrict__ Bt2, int ldb2, int Nsplit,
    const float* __restrict__ bias, const float* __restrict__ bias2,
    const float* __restrict__ addC,
    float* __restrict__ C, int ldc,
    int M, int N, int K) {
  __shared__ short As[64][72];
  __shared__ short Bs[64][72];
  const int tid  = threadIdx.x;
  const int bm   = blockIdx.y * 64;
  const int bn   = blockIdx.x * 64;
  const int srow = tid >> 2;
  const int scol = (tid & 3) << 4;
  const int wv   = tid >> 6;
  const int lane = tid & 63;
  const int fr   = lane & 15;
  const int qd   = lane >> 4;

  f32x4 acc[4] = {};

  const float* arow = A + (size_t)(bm + srow) * lda + scol;
  const int    bro  = bn + srow;
  const bool   bvalid = (bro < N);
  const float* brow =
      (bro >= Nsplit) ? (Bt2 + (size_t)(bro - Nsplit) * ldb2 + scol)
                      : (Bt + (size_t)bro * ldb + scol);

  for (int k0 = 0; k0 < K; k0 += 64) {
    pack16((const float4*)(arow + k0), &As[srow][scol]);
    if (bvalid) {
      pack16((const float4*)(brow + k0), &Bs[srow][scol]);
    } else {
      short8 z = {};
      *(short8*)&Bs[srow][scol]     = z;
      *(short8*)&Bs[srow][scol + 8] = z;
    }
    __syncthreads();
#pragma unroll
    for (int ks = 0; ks < 64; ks += 32) {
      short8 af = *(const short8*)&As[wv * 16 + fr][ks + qd * 8];
#pragma unroll
      for (int f = 0; f < 4; ++f) {
        short8 bf = *(const short8*)&Bs[f * 16 + fr][ks + qd * 8];
        acc[f] = __builtin_amdgcn_mfma_f32_16x16x32_bf16(af, bf, acc[f], 0, 0, 0);
      }
    }
    __syncthreads();
  }

  const int rowb = bm + wv * 16 + (qd << 2);
#pragma unroll
  for (int f = 0; f < 4; ++f) {
    const int col = bn + f * 16 + fr;
    if (col < N) {
      float bval = 0.f;
      if (bias) bval = (col < Nsplit) ? bias[col] : bias2[col - Nsplit];
#pragma unroll
      for (int r = 0; r < 4; ++r) {
        float v = acc[f][r] + bval;
        if (addC) v += addC[(size_t)(rowb + r) * ldc + col];
        C[(size_t)(rowb + r) * ldc + col] = v;
      }
    }
  }
}

// ---------------------------------------------------------------------------
// Per-step GEMM: C[64,N] = A[64,K](fp32) @ Bt[N,K](bf16)^T (+bias) (+addC)
// B pre-converted to bf16 -> half the staging bytes, no cvt VALU work.
// N multiple of 64, K multiple of 64, M fixed at 64.
// ---------------------------------------------------------------------------
__global__ __launch_bounds__(256) void gemm_bf16b(
    const float* __restrict__ A,
    const short* __restrict__ Bt,
    const float* __restrict__ bias,
    const float* __restrict__ addC,
    float* __restrict__ C, int ldc, int N, int K) {
  __shared__ short As[64][72];
  __shared__ short Bs[64][72];
  const int tid  = threadIdx.x;
  const int bn   = blockIdx.x * 64;
  const int srow = tid >> 2;
  const int scol = (tid & 3) << 4;
  const int wv   = tid >> 6;
  const int lane = tid & 63;
  const int fr   = lane & 15;
  const int qd   = lane >> 4;

  f32x4 acc[4] = {};

  const float* arow = A + (size_t)srow * K + scol;
  const short* brow = Bt + (size_t)(bn + srow) * K + scol;

  for (int k0 = 0; k0 < K; k0 += 64) {
    pack16((const float4*)(arow + k0), &As[srow][scol]);
    {
      const short8* p = (const short8*)(brow + k0);
      *(short8*)&Bs[srow][scol]     = p[0];
      *(short8*)&Bs[srow][scol + 8] = p[1];
    }
    __syncthreads();
#pragma unroll
    for (int ks = 0; ks < 64; ks += 32) {
      short8 af = *(const short8*)&As[wv * 16 + fr][ks + qd * 8];
#pragma unroll
      for (int f = 0; f < 4; ++f) {
        short8 bf = *(const short8*)&Bs[f * 16 + fr][ks + qd * 8];
        acc[f] = __builtin_amdgcn_mfma_f32_16x16x32_bf16(af, bf, acc[f], 0, 0, 0);
      }
    }
    __syncthreads();
  }

  const int rowb = wv * 16 + (qd << 2);
#pragma unroll
  for (int f = 0; f < 4; ++f) {
    const int col = bn + f * 16 + fr;
    float bval = bias ? bias[col] : 0.f;
#pragma unroll
    for (int r = 0; r < 4; ++r) {
      float v = acc[f][r] + bval;
      if (addC) v += addC[(size_t)(rowb + r) * ldc + col];
      C[(size_t)(rowb + r) * ldc + col] = v;
    }
  }
}

// ---------------------------------------------------------------------------
// Batched logits GEMM: out_logits = Hall[1024,H] @ Wout[V,H]^T + bout
// M-tile = 128 (halves Wout re-reads vs 64), rows >= 960 discarded.
// Epilogue writes straight into out with row remap (Hall row t*64+b ->
// out row b*T+t, stride V).
// ---------------------------------------------------------------------------
__global__ __launch_bounds__(256) void gemm_logits(
    const float* __restrict__ Hall,
    const float* __restrict__ Wout,
    const float* __restrict__ bout,
    float* __restrict__ out) {
  __shared__ short As[128][72];
  __shared__ short Bs[64][72];
  const int tid  = threadIdx.x;
  const int bm   = blockIdx.y * 128;
  const int bn   = blockIdx.x * 64;
  const int srow = tid >> 2;
  const int scol = (tid & 3) << 4;
  const int wv   = tid >> 6;
  const int lane = tid & 63;
  const int fr   = lane & 15;
  const int qd   = lane >> 4;

  f32x4 acc0[4] = {};
  f32x4 acc1[4] = {};

  const float* arow0 = Hall + (size_t)(bm + srow) * H + scol;
  const float* arow1 = arow0 + (size_t)64 * H;
  const int    bro   = bn + srow;
  const bool   bvalid = (bro < V);
  const float* brow  = Wout + (size_t)bro * H + scol;

  for (int k0 = 0; k0 < H; k0 += 64) {
    pack16((const float4*)(arow0 + k0), &As[srow][scol]);
    pack16((const float4*)(arow1 + k0), &As[srow + 64][scol]);
    if (bvalid) {
      pack16((const float4*)(brow + k0), &Bs[srow][scol]);
    } else {
      short8 z = {};
      *(short8*)&Bs[srow][scol]     = z;
      *(short8*)&Bs[srow][scol + 8] = z;
    }
    __syncthreads();
#pragma unroll
    for (int ks = 0; ks < 64; ks += 32) {
      short8 af0 = *(const short8*)&As[wv * 32 + fr][ks + qd * 8];
      short8 af1 = *(const short8*)&As[wv * 32 + 16 + fr][ks + qd * 8];
#pragma unroll
      for (int f = 0; f < 4; ++f) {
        short8 bf = *(const short8*)&Bs[f * 16 + fr][ks + qd * 8];
        acc0[f] = __builtin_amdgcn_mfma_f32_16x16x32_bf16(af0, bf, acc0[f], 0, 0, 0);
        acc1[f] = __builtin_amdgcn_mfma_f32_16x16x32_bf16(af1, bf, acc1[f], 0, 0, 0);
      }
    }
    __syncthreads();
  }

  // epilogue with (t*64+b) -> (b*T+t) row remap into out (stride V)
  const int r0 = bm + wv * 32 + (qd << 2);
#pragma unroll
  for (int f = 0; f < 4; ++f) {
    const int col = bn + f * 16 + fr;
    if (col < V) {
      const float bval = bout[col];
#pragma unroll
      for (int r = 0; r < 4; ++r) {
        const int row0 = r0 + r;
        if (row0 < 960) {
          out[((size_t)((row0 & 63) * T + (row0 >> 6))) * V + col] = acc0[f][r] + bval;
        }
        const int row1 = r0 + 16 + r;
        if (row1 < 960) {
          out[((size_t)((row1 & 63) * T + (row1 >> 6))) * V + col] = acc1[f][r] + bval;
        }
      }
    }
  }
}

// ---------------------------------------------------------------------------
// E[r=t*B+b, :] = emb[input_token(t,b), :]
// ---------------------------------------------------------------------------
__global__ __launch_bounds__(256) void buildE_kernel(
    const float* __restrict__ emb, const int* __restrict__ tgt,
    float* __restrict__ E) {
  const int r = blockIdx.x;
  const int t = r >> 6;
  const int b = r & 63;
  const int tok = (t == 0) ? 0 : tgt[b * T + (t - 1)];
  const float4* src = (const float4*)(emb + (size_t)tok * H);
  float4* dst = (float4*)(E + (size_t)r * H);
  dst[threadIdx.x] = src[threadIdx.x];
}

// ---------------------------------------------------------------------------
// Attention step (unchanged, verified).
// ---------------------------------------------------------------------------
__global__ __launch_bounds__(256) void attn_kernel(
    const float* __restrict__ qgh, const float* __restrict__ Uk,
    const float* __restrict__ Va, const float* __restrict__ bv,
    const float* __restrict__ enc, float* __restrict__ ctx,
    float* __restrict__ attn_out, int t) {
  __shared__ float qs[H];
  __shared__ float vas[H];
  __shared__ float sc[S];
  const int b   = blockIdx.x;
  const int tid = threadIdx.x;

  for (int i = tid; i < H; i += 256) {
    qs[i]  = qgh[(size_t)b * 4096 + i];
    vas[i] = Va[i];
  }
  __syncthreads();

  const int wave = tid >> 6;
  const int lane = tid & 63;
  for (int s = wave; s < S; s += 4) {
    const float* uk = Uk + ((size_t)(b * S + s)) * H;
    float sum = 0.f;
#pragma unroll 4
    for (int h = lane; h < H; h += 64) {
      sum += vas[h] * fast_tanh(qs[h] + uk[h]);
    }
#pragma unroll
    for (int off = 32; off > 0; off >>= 1) sum += __shfl_down(sum, off);
    if (lane == 0) sc[s] = sum + bv[0];
  }
  __syncthreads();

  if (tid < 64) {
    float v = sc[tid];
    float m = v;
#pragma unroll
    for (int off = 32; off > 0; off >>= 1) m = fmaxf(m, __shfl_xor(m, off));
    float e = __expf(v - m);
    float ssum = e;
#pragma unroll
    for (int off = 32; off > 0; off >>= 1) ssum += __shfl_xor(ssum, off);
    float w = e / ssum;
    sc[tid] = w;
    attn_out[((size_t)b * T + t) * S + tid] = w;
  }
  __syncthreads();

  const int h4 = tid * 4;
  float4 acc = make_float4(0.f, 0.f, 0.f, 0.f);
  const float* eb = enc + (size_t)b * S * H;
#pragma unroll 4
  for (int s = 0; s < S; ++s) {
    float w = sc[s];
    float4 ev = *(const float4*)(eb + (size_t)s * H + h4);
    acc.x += w * ev.x; acc.y += w * ev.y; acc.z += w * ev.z; acc.w += w * ev.w;
  }
  *(float4*)(ctx + (size_t)b * H + h4) = acc;
}

// ---------------------------------------------------------------------------
// GRU pointwise (unchanged).
// ---------------------------------------------------------------------------
__global__ __launch_bounds__(256) void gru_kernel(
    const float* __restrict__ gi, const float* __restrict__ qgh,
    const float* __restrict__ hprev, float* __restrict__ hnew) {
  const int i = blockIdx.x * 256 + threadIdx.x;
  const int b = i >> 10;
  const int h = i & 1023;
  const float* gib = gi + (size_t)b * 3072;
  const float* ghb = qgh + (size_t)b * 4096 + 1024;
  float ir = gib[h], iz = gib[H + h], in_ = gib[2 * H + h];
  float hr = ghb[h], hz = ghb[H + h], hn = ghb[2 * H + h];
  float r = fast_sigmoid(ir + hr);
  float z = fast_sigmoid(iz + hz);
  float n = fast_tanh(in_ + r * hn);
  hnew[i] = (1.f - z) * n + z * hprev[i];
}

// ---------------------------------------------------------------------------
// Batched in-place log-softmax over all 960 (b,t) rows of out (stride V).
// Handles the 16B misalignment of odd-V row starts (head/tail scalars).
// ---------------------------------------------------------------------------
__global__ __launch_bounds__(512) void logsoftmax_inplace(float* __restrict__ out) {
  const int p = blockIdx.x;                 // row index = b*T + t
  float* row = out + (size_t)p * V;
  const int mis  = (int)(((size_t)p * V) & 3);
  const int head = mis ? (4 - mis) : 0;
  const int nv   = (V - head) >> 2;
  const int tail = V - head - (nv << 2);
  float4* row4 = (float4*)(row + head);
  const int tid = threadIdx.x;
  __shared__ float red[8];

  float m = -INFINITY;
  for (int i = tid; i < nv; i += 512) {
    float4 v = row4[i];
    m = fmaxf(fmaxf(v.x, v.y), fmaxf(fmaxf(v.z, v.w), m));
  }
  if (tid < head) m = fmaxf(m, row[tid]);
  if (tid < tail) m = fmaxf(m, row[head + (nv << 2) + tid]);
#pragma unroll
  for (int off = 32; off > 0; off >>= 1) m = fmaxf(m, __shfl_xor(m, off));
  if ((tid & 63) == 0) red[tid >> 6] = m;
  __syncthreads();
  m = red[0];
#pragma unroll
  for (int i = 1; i < 8; ++i) m = fmaxf(m, red[i]);
  __syncthreads();

  float s = 0.f;
  for (int i = tid; i < nv; i += 512) {
    float4 v = row4[i];
    s += __expf(v.x - m) + __expf(v.y - m) + __expf(v.z - m) + __expf(v.w - m);
  }
  if (tid < head) s += __expf(row[tid] - m);
  if (tid < tail) s += __expf(row[head + (nv << 2) + tid] - m);
#pragma unroll
  for (int off = 32; off > 0; off >>= 1) s += __shfl_xor(s, off);
  if ((tid & 63) == 0) red[tid >> 6] = s;
  __syncthreads();
  s = red[0];
#pragma unroll
  for (int i = 1; i < 8; ++i) s += red[i];

  const float lse = m + logf(s);
  for (int i = tid; i < nv; i += 512) {
    float4 v = row4[i];
    v.x -= lse; v.y -= lse; v.z -= lse; v.w -= lse;
    row4[i] = v;
  }
  if (tid < head) row[tid] -= lse;
  if (tid < tail) row[head + (nv << 2) + tid] -= lse;
}

// ---------------------------------------------------------------------------
// Setup helpers: fp32 -> bf16 conversions. FIXED: 16 elements per thread
// (pack16 converts 16 floats), no overlap, no OOB.
// ---------------------------------------------------------------------------
__global__ __launch_bounds__(256) void cvt_bf16_kernel(
    const float* __restrict__ src, short* __restrict__ dst, int n16) {
  const int i = blockIdx.x * 256 + threadIdx.x;  // 16 elems per thread
  if (i >= n16) return;
  pack16((const float4*)(src + (size_t)i * 16), dst + (size_t)i * 16);
}

// Wih2[n,k] = bf16(W_ih[n, H + k]), n in [0,3072), k in [0,1024)
// 64 threads x 16 elems = 1024 = one row per block.
__global__ __launch_bounds__(64) void cvt_wih2_kernel(
    const float* __restrict__ W_ih, short* __restrict__ dst) {
  const int r = blockIdx.x;         // 0..3071
  const int c = threadIdx.x * 16;   // 0..1008
  pack16((const float4*)(W_ih + (size_t)r * 2048 + 1024 + c),
         dst + (size_t)r * 1024 + c);
}

__global__ __launch_bounds__(256) void build_bqgh_kernel(
    const float* __restrict__ ba, const float* __restrict__ bhh,
    float* __restrict__ bq) {
  const int i = blockIdx.x * 256 + threadIdx.x;  // < 4096
  bq[i] = (i < H) ? ba[i] : bhh[i - H];
}

__global__ __launch_bounds__(256) void zero_kernel(float* __restrict__ p, int n) {
  const int i = blockIdx.x * 256 + threadIdx.x;
  if (i < n) p[i] = 0.f;
}

// ---------------------------------------------------------------------------
extern "C" void kernel_launch(void* const* d_in, const int* in_sizes, int n_in,
                              void* d_out, int out_size, void* d_ws, size_t ws_size,
                              hipStream_t stream) {
  const float* enc    = (const float*)d_in[0];
  const float* h_init = (const float*)d_in[1];
  const int*   tgt    = (const int*)d_in[2];
  const float* emb    = (const float*)d_in[3];
  const float* Wa     = (const float*)d_in[4];
  const float* ba     = (const float*)d_in[5];
  const float* Ua     = (const float*)d_in[6];
  const float* bu     = (const float*)d_in[7];
  const float* Va     = (const float*)d_in[8];
  const float* bv     = (const float*)d_in[9];
  const float* W_ih   = (const float*)d_in[10];
  const float* W_hh   = (const float*)d_in[11];
  const float* b_ih   = (const float*)d_in[12];
  const float* b_hh   = (const float*)d_in[13];
  const float* Wout   = (const float*)d_in[14];
  const float* bout   = (const float*)d_in[15];

  float* out = (float*)d_out;
  float* ws  = (float*)d_ws;

  const int BIG = 1 << 30;

  // Workspace layout (floats)
  float* Uk      = ws;                              // 4096*1024
  float* E       = Uk + (size_t)4096 * 1024;        // 960*1024
  float* gi_e    = E + (size_t)960 * 1024;          // 960*3072
  float* qgh     = gi_e + (size_t)960 * 3072;       // 64*4096
  float* ctx     = qgh + (size_t)64 * 4096;         // 64*1024
  float* gi      = ctx + (size_t)64 * 1024;         // 64*3072
  float* Hall    = gi + (size_t)64 * 3072;          // 1024*1024 (rows>=960 pad)
  float* bqgh    = Hall + (size_t)1024 * 1024;      // 4096
  short* Wqgh16  = (short*)(bqgh + 4096);           // 4096*1024 bf16
  short* Wih2_16 = Wqgh16 + (size_t)4096 * 1024;    // 3072*1024 bf16

  const size_t OFF_HT   = (size_t)B * T * V;
  const size_t OFF_ATTN = OFF_HT + (size_t)B * H;

  // ---- one-time setup ----
  buildE_kernel<<<T * B, 256, 0, stream>>>(emb, tgt, E);
  // Uk = enc @ Ua^T + bu
  gemm_mfma<<<dim3(16, 64), 256, 0, stream>>>(
      enc, H, Ua, H, Ua, H, BIG, bu, nullptr, nullptr, Uk, H, 4096, H, H);
  // gi_e = E @ W_ih[:, :H]^T + b_ih
  gemm_mfma<<<dim3(48, 15), 256, 0, stream>>>(
      E, H, W_ih, 2 * H, W_ih, 2 * H, BIG, b_ih, nullptr, nullptr,
      gi_e, 3 * H, 960, 3 * H, H);
  // bf16 weight prepacks (16 elems/thread)
  cvt_bf16_kernel<<<256, 256, 0, stream>>>(Wa, Wqgh16, 65536);      // 1024*1024
  cvt_bf16_kernel<<<768, 256, 0, stream>>>(W_hh, Wqgh16 + (size_t)1024 * 1024,
                                           196608);                 // 3072*1024
  cvt_wih2_kernel<<<3072, 64, 0, stream>>>(W_ih, Wih2_16);
  build_bqgh_kernel<<<16, 256, 0, stream>>>(ba, b_hh, bqgh);
  zero_kernel<<<256, 256, 0, stream>>>(Hall + (size_t)960 * 1024, 64 * 1024);

  // ---- serial recurrence (logits hoisted out of the loop) ----
  const float* hc = h_init;
  for (int t = 0; t < T; ++t) {
    float* hn = Hall + (size_t)t * 64 * 1024;
    // qgh = h @ [Wa; W_hh]^T + [ba; b_hh]
    gemm_bf16b<<<dim3(64), 256, 0, stream>>>(
        hc, Wqgh16, bqgh, nullptr, qgh, 4096, 4096, H);
    attn_kernel<<<B, 256, 0, stream>>>(qgh, Uk, Va, bv, enc, ctx,
                                       out + OFF_ATTN, t);
    // gi = ctx @ W_ih[:, H:]^T + gi_e[t]
    gemm_bf16b<<<dim3(48), 256, 0, stream>>>(
        ctx, Wih2_16, nullptr, gi_e + (size_t)t * 64 * 3072, gi, 3072, 3072, H);
    gru_kernel<<<(B * H) / 256, 256, 0, stream>>>(gi, qgh, hc, hn);
    hc = hn;
  }

  // ---- batched logits + log-softmax ----
  gemm_logits<<<dim3((V + 63) / 64, 8), 256, 0, stream>>>(Hall, Wout, bout, out);
  logsoftmax_inplace<<<960, 512, 0, stream>>>(out);

  // hT
  hipMemcpyAsync(out + OFF_HT, hc, (size_t)B * H * sizeof(float),
                 hipMemcpyDeviceToDevice, stream);
}

// Round 3
// 1873.892 us; speedup vs baseline: 1.7608x; 1.2956x over previous
//
#include <hip/hip_runtime.h>
#include <math.h>

// Problem constants
#define B 64
#define S 64
#define T 15
#define H 1024
#define V 50257
// SOS token = 0

typedef __attribute__((ext_vector_type(8))) short short8;
typedef __attribute__((ext_vector_type(4))) float f32x4;

// fp32 -> bf16 with round-to-nearest-even
__device__ __forceinline__ short f2bf(float x) {
  unsigned u = __float_as_uint(x);
  u += 0x7fffu + ((u >> 16) & 1u);
  return (short)(u >> 16);
}

__device__ __forceinline__ float fast_sigmoid(float x) {
  return 1.f / (1.f + __expf(-x));
}
__device__ __forceinline__ float fast_tanh(float x) {
  x = fminf(15.f, fmaxf(-15.f, x));
  float e = __expf(2.f * x);
  return (e - 1.f) / (e + 1.f);
}

// Pack 16 fp32 (from regs) -> 16 bf16 (2 short8) at dst, dst+8
__device__ __forceinline__ void pack16r(float4 v0, float4 v1, float4 v2, float4 v3,
                                        short* dst) {
  union PK { short8 v; short s[8]; } lo, hi;
  lo.s[0] = f2bf(v0.x); lo.s[1] = f2bf(v0.y); lo.s[2] = f2bf(v0.z); lo.s[3] = f2bf(v0.w);
  lo.s[4] = f2bf(v1.x); lo.s[5] = f2bf(v1.y); lo.s[6] = f2bf(v1.z); lo.s[7] = f2bf(v1.w);
  hi.s[0] = f2bf(v2.x); hi.s[1] = f2bf(v2.y); hi.s[2] = f2bf(v2.z); hi.s[3] = f2bf(v2.w);
  hi.s[4] = f2bf(v3.x); hi.s[5] = f2bf(v3.y); hi.s[6] = f2bf(v3.z); hi.s[7] = f2bf(v3.w);
  *(short8*)dst = lo.v;
  *(short8*)(dst + 8) = hi.v;
}

__device__ __forceinline__ void pack16(const float4* __restrict__ p, short* dst) {
  pack16r(p[0], p[1], p[2], p[3], dst);
}

// ---------------------------------------------------------------------------
// Generic MFMA GEMM (verified), fp32 A and B, split-B. Setup GEMMs only.
// ---------------------------------------------------------------------------
__global__ __launch_bounds__(256) void gemm_mfma(
    const float* __restrict__ A, int lda,
    const float* __restrict__ Bt, int ldb,
    const float* __restrict__ Bt2, int ldb2, int Nsplit,
    const float* __restrict__ bias, const float* __restrict__ bias2,
    const float* __restrict__ addC,
    float* __restrict__ C, int ldc,
    int M, int N, int K) {
  __shared__ short As[64][72];
  __shared__ short Bs[64][72];
  const int tid  = threadIdx.x;
  const int bm   = blockIdx.y * 64;
  const int bn   = blockIdx.x * 64;
  const int srow = tid >> 2;
  const int scol = (tid & 3) << 4;
  const int wv   = tid >> 6;
  const int lane = tid & 63;
  const int fr   = lane & 15;
  const int qd   = lane >> 4;

  f32x4 acc[4] = {};

  const float* arow = A + (size_t)(bm + srow) * lda + scol;
  const int    bro  = bn + srow;
  const bool   bvalid = (bro < N);
  const float* brow =
      (bro >= Nsplit) ? (Bt2 + (size_t)(bro - Nsplit) * ldb2 + scol)
                      : (Bt + (size_t)bro * ldb + scol);

  for (int k0 = 0; k0 < K; k0 += 64) {
    pack16((const float4*)(arow + k0), &As[srow][scol]);
    if (bvalid) {
      pack16((const float4*)(brow + k0), &Bs[srow][scol]);
    } else {
      short8 z = {};
      *(short8*)&Bs[srow][scol]     = z;
      *(short8*)&Bs[srow][scol + 8] = z;
    }
    __syncthreads();
#pragma unroll
    for (int ks = 0; ks < 64; ks += 32) {
      short8 af = *(const short8*)&As[wv * 16 + fr][ks + qd * 8];
#pragma unroll
      for (int f = 0; f < 4; ++f) {
        short8 bf = *(const short8*)&Bs[f * 16 + fr][ks + qd * 8];
        acc[f] = __builtin_amdgcn_mfma_f32_16x16x32_bf16(af, bf, acc[f], 0, 0, 0);
      }
    }
    __syncthreads();
  }

  const int rowb = bm + wv * 16 + (qd << 2);
#pragma unroll
  for (int f = 0; f < 4; ++f) {
    const int col = bn + f * 16 + fr;
    if (col < N) {
      float bval = 0.f;
      if (bias) bval = (col < Nsplit) ? bias[col] : bias2[col - Nsplit];
#pragma unroll
      for (int r = 0; r < 4; ++r) {
        float v = acc[f][r] + bval;
        if (addC) v += addC[(size_t)(rowb + r) * ldc + col];
        C[(size_t)(rowb + r) * ldc + col] = v;
      }
    }
  }
}

// ---------------------------------------------------------------------------
// Per-step GEMM: C[64,N] = A[64,K](fp32) @ Bt[N,K](bf16)^T (+bias)
// Double-buffered: prefetch next K-tile into regs while computing current.
// ---------------------------------------------------------------------------
__global__ __launch_bounds__(256) void gemm_bf16b(
    const float* __restrict__ A,
    const short* __restrict__ Bt,
    const float* __restrict__ bias,
    float* __restrict__ C, int ldc, int N, int K) {
  __shared__ short As[64][72];
  __shared__ short Bs[64][72];
  const int tid  = threadIdx.x;
  const int bn   = blockIdx.x * 64;
  const int srow = tid >> 2;
  const int scol = (tid & 3) << 4;
  const int wv   = tid >> 6;
  const int lane = tid & 63;
  const int fr   = lane & 15;
  const int qd   = lane >> 4;

  f32x4 acc[4] = {};

  const float* arow = A + (size_t)srow * K + scol;
  const short* brow = Bt + (size_t)(bn + srow) * K + scol;

  float4 a0, a1, a2, a3;
  short8 bq0, bq1;
  {
    const float4* p = (const float4*)arow;
    a0 = p[0]; a1 = p[1]; a2 = p[2]; a3 = p[3];
    const short8* q = (const short8*)brow;
    bq0 = q[0]; bq1 = q[1];
  }

  for (int k0 = 0; k0 < K; k0 += 64) {
    pack16r(a0, a1, a2, a3, &As[srow][scol]);
    *(short8*)&Bs[srow][scol]     = bq0;
    *(short8*)&Bs[srow][scol + 8] = bq1;
    __syncthreads();
    if (k0 + 64 < K) {
      const float4* p = (const float4*)(arow + k0 + 64);
      a0 = p[0]; a1 = p[1]; a2 = p[2]; a3 = p[3];
      const short8* q = (const short8*)(brow + k0 + 64);
      bq0 = q[0]; bq1 = q[1];
    }
#pragma unroll
    for (int ks = 0; ks < 64; ks += 32) {
      short8 af = *(const short8*)&As[wv * 16 + fr][ks + qd * 8];
#pragma unroll
      for (int f = 0; f < 4; ++f) {
        short8 bf = *(const short8*)&Bs[f * 16 + fr][ks + qd * 8];
        acc[f] = __builtin_amdgcn_mfma_f32_16x16x32_bf16(af, bf, acc[f], 0, 0, 0);
      }
    }
    __syncthreads();
  }

  const int rowb = wv * 16 + (qd << 2);
#pragma unroll
  for (int f = 0; f < 4; ++f) {
    const int col = bn + f * 16 + fr;
    float bval = bias ? bias[col] : 0.f;
#pragma unroll
    for (int r = 0; r < 4; ++r) {
      C[(size_t)(rowb + r) * ldc + col] = acc[f][r] + bval;
    }
  }
}

// ---------------------------------------------------------------------------
// Fused gi-GEMM + GRU. Grid = 16 blocks; block x owns h-cols [64x, 64x+64)
// for ALL three gates (192 B-rows). Epilogue computes GRU pointwise -> hnew.
//   gi[b, g*1024+h] = ctx[b] . Wih2[g*1024+h] + gie[b, g*1024+h]
//   gh from qgh cols [1024..4096); hnew = (1-z)*n + z*hprev
// ---------------------------------------------------------------------------
__global__ __launch_bounds__(256) void gemm_gru(
    const float* __restrict__ ctx,     // [64,1024] fp32
    const short* __restrict__ Wih2,    // [3072,1024] bf16
    const float* __restrict__ gie,     // this step's gi_e slice [64,3072]
    const float* __restrict__ qgh,     // [64,4096], gh at col 1024
    const float* __restrict__ hprev,   // [64,1024]
    float* __restrict__ hnew) {        // [64,1024]
  __shared__ short As[64][72];
  __shared__ short Bs[192][72];
  const int tid  = threadIdx.x;
  const int x    = blockIdx.x;         // h-tile 0..15
  const int srow = tid >> 2;
  const int scol = (tid & 3) << 4;
  const int wv   = tid >> 6;
  const int lane = tid & 63;
  const int fr   = lane & 15;
  const int qd   = lane >> 4;

  f32x4 acc[12] = {};

  const float* arow = ctx + (size_t)srow * H + scol;

  // B staging: 3 chunks per thread; chunk c -> row rr=c>>2 (0..191),
  // col (c&3)*16; global row n = (rr>>6)*1024 + x*64 + (rr&63)
  const short* bbase[3];
  int brr[3], bcc[3];
#pragma unroll
  for (int j = 0; j < 3; ++j) {
    const int c  = tid + 256 * j;
    const int rr = c >> 2;
    const int cc = (c & 3) << 4;
    const int n  = ((rr >> 6) << 10) + (x << 6) + (rr & 63);
    bbase[j] = Wih2 + (size_t)n * H + cc;
    brr[j] = rr; bcc[j] = cc;
  }

  float4 a0, a1, a2, a3;
  short8 bq0[3], bq1[3];
  {
    const float4* p = (const float4*)arow;
    a0 = p[0]; a1 = p[1]; a2 = p[2]; a3 = p[3];
#pragma unroll
    for (int j = 0; j < 3; ++j) {
      const short8* q = (const short8*)bbase[j];
      bq0[j] = q[0]; bq1[j] = q[1];
    }
  }

  for (int k0 = 0; k0 < H; k0 += 64) {
    pack16r(a0, a1, a2, a3, &As[srow][scol]);
#pragma unroll
    for (int j = 0; j < 3; ++j) {
      *(short8*)&Bs[brr[j]][bcc[j]]     = bq0[j];
      *(short8*)&Bs[brr[j]][bcc[j] + 8] = bq1[j];
    }
    __syncthreads();
    if (k0 + 64 < H) {
      const float4* p = (const float4*)(arow + k0 + 64);
      a0 = p[0]; a1 = p[1]; a2 = p[2]; a3 = p[3];
#pragma unroll
      for (int j = 0; j < 3; ++j) {
        const short8* q = (const short8*)(bbase[j] + k0 + 64);
        bq0[j] = q[0]; bq1[j] = q[1];
      }
    }
#pragma unroll
    for (int ks = 0; ks < 64; ks += 32) {
      short8 af = *(const short8*)&As[wv * 16 + fr][ks + qd * 8];
#pragma unroll
      for (int f = 0; f < 12; ++f) {
        short8 bf = *(const short8*)&Bs[f * 16 + fr][ks + qd * 8];
        acc[f] = __builtin_amdgcn_mfma_f32_16x16x32_bf16(af, bf, acc[f], 0, 0, 0);
      }
    }
    __syncthreads();
  }

  // GRU epilogue. Frag f = g*4+fc covers Bs rows 64g + 16fc + fr
  const int rowb = wv * 16 + (qd << 2);
#pragma unroll
  for (int fc = 0; fc < 4; ++fc) {
    const int h = (x << 6) + (fc << 4) + fr;
#pragma unroll
    for (int r = 0; r < 4; ++r) {
      const int b = rowb + r;
      const float* gieb = gie + (size_t)b * 3072;
      const float* ghb  = qgh + (size_t)b * 4096 + 1024;
      float i0 = acc[0 * 4 + fc][r] + gieb[h];
      float i1 = acc[1 * 4 + fc][r] + gieb[1024 + h];
      float i2 = acc[2 * 4 + fc][r] + gieb[2048 + h];
      float hr = ghb[h], hz = ghb[1024 + h], hn = ghb[2048 + h];
      float rr_ = fast_sigmoid(i0 + hr);
      float zz  = fast_sigmoid(i1 + hz);
      float nn  = fast_tanh(i2 + rr_ * hn);
      hnew[(size_t)b * H + h] = (1.f - zz) * nn + zz * hprev[(size_t)b * H + h];
    }
  }
}

// ---------------------------------------------------------------------------
// Batched logits GEMM: out = Hall[1024,H](fp32) @ Wout16[V,H](bf16)^T + bout
// M-tile 128, double-buffered staging, bf16 B (no conversion in-loop).
// Row remap (t*64+b) -> (b*T+t) into out, stride V.
// ---------------------------------------------------------------------------
__global__ __launch_bounds__(256) void gemm_logits(
    const float* __restrict__ Hall,
    const short* __restrict__ Wout16,
    const float* __restrict__ bout,
    float* __restrict__ out) {
  __shared__ short As[128][72];
  __shared__ short Bs[64][72];
  const int tid  = threadIdx.x;
  const int bm   = blockIdx.y * 128;
  const int bn   = blockIdx.x * 64;
  const int srow = tid >> 2;
  const int scol = (tid & 3) << 4;
  const int wv   = tid >> 6;
  const int lane = tid & 63;
  const int fr   = lane & 15;
  const int qd   = lane >> 4;

  f32x4 acc0[4] = {};
  f32x4 acc1[4] = {};

  const float* arow0 = Hall + (size_t)(bm + srow) * H + scol;
  const float* arow1 = arow0 + (size_t)64 * H;
  const int    bro   = bn + srow;
  const bool   bvalid = (bro < V);
  const short* brow  = Wout16 + (size_t)bro * H + scol;

  float4 a0, a1, a2, a3, a4, a5, a6, a7;
  short8 bq0 = {}, bq1 = {};
  {
    const float4* p0 = (const float4*)arow0;
    a0 = p0[0]; a1 = p0[1]; a2 = p0[2]; a3 = p0[3];
    const float4* p1 = (const float4*)arow1;
    a4 = p1[0]; a5 = p1[1]; a6 = p1[2]; a7 = p1[3];
    if (bvalid) {
      const short8* q = (const short8*)brow;
      bq0 = q[0]; bq1 = q[1];
    }
  }

  for (int k0 = 0; k0 < H; k0 += 64) {
    pack16r(a0, a1, a2, a3, &As[srow][scol]);
    pack16r(a4, a5, a6, a7, &As[srow + 64][scol]);
    *(short8*)&Bs[srow][scol]     = bq0;
    *(short8*)&Bs[srow][scol + 8] = bq1;
    __syncthreads();
    if (k0 + 64 < H) {
      const float4* p0 = (const float4*)(arow0 + k0 + 64);
      a0 = p0[0]; a1 = p0[1]; a2 = p0[2]; a3 = p0[3];
      const float4* p1 = (const float4*)(arow1 + k0 + 64);
      a4 = p1[0]; a5 = p1[1]; a6 = p1[2]; a7 = p1[3];
      if (bvalid) {
        const short8* q = (const short8*)(brow + k0 + 64);
        bq0 = q[0]; bq1 = q[1];
      }
    }
#pragma unroll
    for (int ks = 0; ks < 64; ks += 32) {
      short8 af0 = *(const short8*)&As[wv * 32 + fr][ks + qd * 8];
      short8 af1 = *(const short8*)&As[wv * 32 + 16 + fr][ks + qd * 8];
#pragma unroll
      for (int f = 0; f < 4; ++f) {
        short8 bf = *(const short8*)&Bs[f * 16 + fr][ks + qd * 8];
        acc0[f] = __builtin_amdgcn_mfma_f32_16x16x32_bf16(af0, bf, acc0[f], 0, 0, 0);
        acc1[f] = __builtin_amdgcn_mfma_f32_16x16x32_bf16(af1, bf, acc1[f], 0, 0, 0);
      }
    }
    __syncthreads();
  }

  const int r0 = bm + wv * 32 + (qd << 2);
#pragma unroll
  for (int f = 0; f < 4; ++f) {
    const int col = bn + f * 16 + fr;
    if (col < V) {
      const float bval = bout[col];
#pragma unroll
      for (int r = 0; r < 4; ++r) {
        const int row0 = r0 + r;
        if (row0 < 960) {
          out[((size_t)((row0 & 63) * T + (row0 >> 6))) * V + col] = acc0[f][r] + bval;
        }
        const int row1 = r0 + 16 + r;
        if (row1 < 960) {
          out[((size_t)((row1 & 63) * T + (row1 >> 6))) * V + col] = acc1[f][r] + bval;
        }
      }
    }
  }
}

// ---------------------------------------------------------------------------
// E[r=t*B+b, :] = emb[input_token(t,b), :]
// ---------------------------------------------------------------------------
__global__ __launch_bounds__(256) void buildE_kernel(
    const float* __restrict__ emb, const int* __restrict__ tgt,
    float* __restrict__ E) {
  const int r = blockIdx.x;
  const int t = r >> 6;
  const int b = r & 63;
  const int tok = (t == 0) ? 0 : tgt[b * T + (t - 1)];
  const float4* src = (const float4*)(emb + (size_t)tok * H);
  float4* dst = (float4*)(E + (size_t)r * H);
  dst[threadIdx.x] = src[threadIdx.x];
}

// ---------------------------------------------------------------------------
// Attention step: 512 threads (8 waves) to hide transcendental latency.
// Per-element math identical to the 256-thread version.
// ---------------------------------------------------------------------------
__global__ __launch_bounds__(512) void attn_kernel(
    const float* __restrict__ qgh, const float* __restrict__ Uk,
    const float* __restrict__ Va, const float* __restrict__ bv,
    const float* __restrict__ enc, float* __restrict__ ctx,
    float* __restrict__ attn_out, int t) {
  __shared__ float qs[H];
  __shared__ float vas[H];
  __shared__ float sc[S];
  const int b   = blockIdx.x;
  const int tid = threadIdx.x;

  for (int i = tid; i < H; i += 512) {
    qs[i]  = qgh[(size_t)b * 4096 + i];
    vas[i] = Va[i];
  }
  __syncthreads();

  const int wave = tid >> 6;
  const int lane = tid & 63;
  for (int s = wave; s < S; s += 8) {
    const float* uk = Uk + ((size_t)(b * S + s)) * H;
    float sum = 0.f;
#pragma unroll 4
    for (int h = lane; h < H; h += 64) {
      sum += vas[h] * fast_tanh(qs[h] + uk[h]);
    }
#pragma unroll
    for (int off = 32; off > 0; off >>= 1) sum += __shfl_down(sum, off);
    if (lane == 0) sc[s] = sum + bv[0];
  }
  __syncthreads();

  if (tid < 64) {
    float v = sc[tid];
    float m = v;
#pragma unroll
    for (int off = 32; off > 0; off >>= 1) m = fmaxf(m, __shfl_xor(m, off));
    float e = __expf(v - m);
    float ssum = e;
#pragma unroll
    for (int off = 32; off > 0; off >>= 1) ssum += __shfl_xor(ssum, off);
    float w = e / ssum;
    sc[tid] = w;
    attn_out[((size_t)b * T + t) * S + tid] = w;
  }
  __syncthreads();

  const int h2 = tid * 2;  // 512*2 = 1024 = H
  float ax = 0.f, ay = 0.f;
  const float* eb = enc + (size_t)b * S * H;
#pragma unroll 4
  for (int s = 0; s < S; ++s) {
    float w = sc[s];
    float2 ev = *(const float2*)(eb + (size_t)s * H + h2);
    ax += w * ev.x; ay += w * ev.y;
  }
  *(float2*)(ctx + (size_t)b * H + h2) = make_float2(ax, ay);
}

// ---------------------------------------------------------------------------
// Batched in-place log-softmax, online max+sum (2 row passes instead of 3).
// ---------------------------------------------------------------------------
__global__ __launch_bounds__(512) void logsoftmax_inplace(float* __restrict__ out) {
  const int p = blockIdx.x;                 // row index = b*T + t
  float* row = out + (size_t)p * V;
  const int mis  = (int)(((size_t)p * V) & 3);
  const int head = mis ? (4 - mis) : 0;
  const int nv   = (V - head) >> 2;
  const int tail = V - head - (nv << 2);
  float4* row4 = (float4*)(row + head);
  const int tid = threadIdx.x;
  __shared__ float redm[8];
  __shared__ float reds[8];

  float m = -INFINITY, s = 0.f;
  for (int i = tid; i < nv; i += 512) {
    float4 v = row4[i];
    float vm = fmaxf(fmaxf(v.x, v.y), fmaxf(v.z, v.w));
    if (vm > m) { s *= __expf(m - vm); m = vm; }
    s += __expf(v.x - m) + __expf(v.y - m) + __expf(v.z - m) + __expf(v.w - m);
  }
  if (tid < head) {
    float v = row[tid];
    if (v > m) { s *= __expf(m - v); m = v; }
    s += __expf(v - m);
  }
  if (tid < tail) {
    float v = row[head + (nv << 2) + tid];
    if (v > m) { s *= __expf(m - v); m = v; }
    s += __expf(v - m);
  }
#pragma unroll
  for (int off = 32; off > 0; off >>= 1) {
    float mo = __shfl_xor(m, off);
    float so = __shfl_xor(s, off);
    float M = fmaxf(m, mo);
    s = s * __expf(m - M) + so * __expf(mo - M);
    m = M;
  }
  if ((tid & 63) == 0) { redm[tid >> 6] = m; reds[tid >> 6] = s; }
  __syncthreads();
  {
    float M = redm[0], SS = reds[0];
#pragma unroll
    for (int i = 1; i < 8; ++i) {
      float mo = redm[i], so = reds[i];
      float Mn = fmaxf(M, mo);
      SS = SS * __expf(M - Mn) + so * __expf(mo - Mn);
      M = Mn;
    }
    m = M; s = SS;
  }

  const float lse = m + logf(s);
  for (int i = tid; i < nv; i += 512) {
    float4 v = row4[i];
    v.x -= lse; v.y -= lse; v.z -= lse; v.w -= lse;
    row4[i] = v;
  }
  if (tid < head) row[tid] -= lse;
  if (tid < tail) row[head + (nv << 2) + tid] -= lse;
}

// ---------------------------------------------------------------------------
// Setup helpers
// ---------------------------------------------------------------------------
__global__ __launch_bounds__(256) void cvt_bf16_kernel(
    const float* __restrict__ src, short* __restrict__ dst, int n16) {
  const int i = blockIdx.x * 256 + threadIdx.x;  // 16 elems per thread
  if (i >= n16) return;
  pack16((const float4*)(src + (size_t)i * 16), dst + (size_t)i * 16);
}

// Wih2[n,k] = bf16(W_ih[n, H + k])
__global__ __launch_bounds__(64) void cvt_wih2_kernel(
    const float* __restrict__ W_ih, short* __restrict__ dst) {
  const int r = blockIdx.x;         // 0..3071
  const int c = threadIdx.x * 16;   // 0..1008
  pack16((const float4*)(W_ih + (size_t)r * 2048 + 1024 + c),
         dst + (size_t)r * 1024 + c);
}

__global__ __launch_bounds__(256) void build_bqgh_kernel(
    const float* __restrict__ ba, const float* __restrict__ bhh,
    float* __restrict__ bq) {
  const int i = blockIdx.x * 256 + threadIdx.x;  // < 4096
  bq[i] = (i < H) ? ba[i] : bhh[i - H];
}

__global__ __launch_bounds__(256) void zero_kernel(float* __restrict__ p, int n) {
  const int i = blockIdx.x * 256 + threadIdx.x;
  if (i < n) p[i] = 0.f;
}

// ---------------------------------------------------------------------------
extern "C" void kernel_launch(void* const* d_in, const int* in_sizes, int n_in,
                              void* d_out, int out_size, void* d_ws, size_t ws_size,
                              hipStream_t stream) {
  const float* enc    = (const float*)d_in[0];
  const float* h_init = (const float*)d_in[1];
  const int*   tgt    = (const int*)d_in[2];
  const float* emb    = (const float*)d_in[3];
  const float* Wa     = (const float*)d_in[4];
  const float* ba     = (const float*)d_in[5];
  const float* Ua     = (const float*)d_in[6];
  const float* bu     = (const float*)d_in[7];
  const float* Va     = (const float*)d_in[8];
  const float* bv     = (const float*)d_in[9];
  const float* W_ih   = (const float*)d_in[10];
  const float* W_hh   = (const float*)d_in[11];
  const float* b_ih   = (const float*)d_in[12];
  const float* b_hh   = (const float*)d_in[13];
  const float* Wout   = (const float*)d_in[14];
  const float* bout   = (const float*)d_in[15];

  float* out = (float*)d_out;
  float* ws  = (float*)d_ws;

  const int BIG = 1 << 30;

  // Workspace layout (floats)
  float* Uk      = ws;                              // 4096*1024
  float* E       = Uk + (size_t)4096 * 1024;        // 960*1024
  float* gi_e    = E + (size_t)960 * 1024;          // 960*3072
  float* qgh     = gi_e + (size_t)960 * 3072;       // 64*4096
  float* ctx     = qgh + (size_t)64 * 4096;         // 64*1024
  float* gi      = ctx + (size_t)64 * 1024;         // 64*3072 (unused, layout keep)
  float* Hall    = gi + (size_t)64 * 3072;          // 1024*1024 (rows>=960 pad)
  float* bqgh    = Hall + (size_t)1024 * 1024;      // 4096
  short* Wqgh16  = (short*)(bqgh + 4096);           // 4096*1024 bf16
  short* Wih2_16 = Wqgh16 + (size_t)4096 * 1024;    // 3072*1024 bf16
  short* Wout16  = Wih2_16 + (size_t)3072 * 1024;   // 50257*1024 bf16 (~103 MB)

  const size_t OFF_HT   = (size_t)B * T * V;
  const size_t OFF_ATTN = OFF_HT + (size_t)B * H;

  // ---- one-time setup ----
  buildE_kernel<<<T * B, 256, 0, stream>>>(emb, tgt, E);
  // Uk = enc @ Ua^T + bu
  gemm_mfma<<<dim3(16, 64), 256, 0, stream>>>(
      enc, H, Ua, H, Ua, H, BIG, bu, nullptr, nullptr, Uk, H, 4096, H, H);
  // gi_e = E @ W_ih[:, :H]^T + b_ih
  gemm_mfma<<<dim3(48, 15), 256, 0, stream>>>(
      E, H, W_ih, 2 * H, W_ih, 2 * H, BIG, b_ih, nullptr, nullptr,
      gi_e, 3 * H, 960, 3 * H, H);
  // bf16 weight prepacks (16 elems/thread)
  cvt_bf16_kernel<<<256, 256, 0, stream>>>(Wa, Wqgh16, 65536);      // 1024*1024
  cvt_bf16_kernel<<<768, 256, 0, stream>>>(W_hh, Wqgh16 + (size_t)1024 * 1024,
                                           196608);                 // 3072*1024
  cvt_wih2_kernel<<<3072, 64, 0, stream>>>(W_ih, Wih2_16);
  cvt_bf16_kernel<<<12565, 256, 0, stream>>>(Wout, Wout16, 3216448); // 50257*1024/16
  build_bqgh_kernel<<<16, 256, 0, stream>>>(ba, b_hh, bqgh);
  zero_kernel<<<256, 256, 0, stream>>>(Hall + (size_t)960 * 1024, 64 * 1024);

  // ---- serial recurrence (3 kernels/step) ----
  const float* hc = h_init;
  for (int t = 0; t < T; ++t) {
    float* hn = Hall + (size_t)t * 64 * 1024;
    // qgh = h @ [Wa; W_hh]^T + [ba; b_hh]
    gemm_bf16b<<<dim3(64), 256, 0, stream>>>(
        hc, Wqgh16, bqgh, qgh, 4096, 4096, H);
    attn_kernel<<<B, 512, 0, stream>>>(qgh, Uk, Va, bv, enc, ctx,
                                       out + OFF_ATTN, t);
    // gi GEMM + GRU fused -> hn
    gemm_gru<<<16, 256, 0, stream>>>(ctx, Wih2_16, gi_e + (size_t)t * 64 * 3072,
                                     qgh, hc, hn);
    hc = hn;
  }

  // ---- batched logits + log-softmax ----
  gemm_logits<<<dim3((V + 63) / 64, 8), 256, 0, stream>>>(Hall, Wout16, bout, out);
  logsoftmax_inplace<<<960, 512, 0, stream>>>(out);

  // hT
  hipMemcpyAsync(out + OFF_HT, hc, (size_t)B * H * sizeof(float),
                 hipMemcpyDeviceToDevice, stream);
}